// Round 21
// baseline (260.634 us; speedup 1.0000x reference)
//
#include <hip/hip_runtime.h>
#include <stdint.h>

#define B_ 2
#define T_ 2048
#define C_ 2048
#define H_ 16
#define D_ 128
#define KSP 64
#define C3 6144   // 3*C_

typedef __attribute__((ext_vector_type(4))) float f32x4;
typedef __attribute__((ext_vector_type(8))) _Float16 f16x8;
typedef __attribute__((ext_vector_type(4))) _Float16 f16x4;
typedef __attribute__((ext_vector_type(2))) _Float16 f16x2;

// global -> LDS async copy, 16B per lane. LDS dest is wave-uniform base + lane*16.
__device__ __forceinline__ void gload16(const void* g, void* l) {
  __builtin_amdgcn_global_load_lds(
      (__attribute__((address_space(1))) void*)(uintptr_t)g,
      (__attribute__((address_space(3))) void*)(uint32_t)(uintptr_t)l,
      16, 0, 0);
}

// ---------------- merged prep: x->f16 cvt + W_attn/W_proj transpose-convert ----------------
// blocks [0,2048): cvt (4096 elem/block = 8.4M total); [2048,14336): Wa tiles; [14336,18432): Wp.
__global__ __launch_bounds__(256) void k_prep(const float* __restrict__ x,
                                              _Float16* __restrict__ x16,
                                              const float* __restrict__ Wa,
                                              _Float16* __restrict__ WaT,
                                              const float* __restrict__ Wp,
                                              _Float16* __restrict__ WpT) {
  __shared__ float tile[32][33];
  const int b = blockIdx.x;
  const int tid = threadIdx.x;
  if (b < 2048) {
    const int base = b * 4096;
#pragma unroll
    for (int p = 0; p < 4; ++p) {
      const int i = base + p * 1024 + tid * 4;
      const float4 v = *(const float4*)(x + i);
      f16x4 o;
      o.x = (_Float16)v.x; o.y = (_Float16)v.y; o.z = (_Float16)v.z; o.w = (_Float16)v.w;
      *(f16x4*)(x16 + i) = o;
    }
    return;
  }
  const float* W;
  _Float16* WT;
  int n0, k0, N;
  if (b < 14336) {
    const int t = b - 2048;          // Wa: 192 x 64 tiles (N=6144, K=2048)
    W = Wa; WT = WaT; N = C3;
    n0 = (t % 192) * 32;
    k0 = (t / 192) * 32;
  } else {
    const int t = b - 14336;         // Wp: 64 x 64 tiles (N=2048, K=2048)
    W = Wp; WT = WpT; N = C_;
    n0 = (t % 64) * 32;
    k0 = (t / 64) * 32;
  }
  const int tx = tid & 31, ty = tid >> 5;  // 32 x 8
#pragma unroll
  for (int r = 0; r < 4; ++r)
    tile[ty + r * 8][tx] = W[(size_t)(k0 + ty + r * 8) * N + n0 + tx];
  __syncthreads();
#pragma unroll
  for (int r = 0; r < 4; ++r)
    WT[(size_t)(n0 + ty + r * 8) * C_ + k0 + tx] = (_Float16)tile[tx][ty + r * 8];
}

// ---------------- GEMM1 (R21): m97-regime 128x128 tile, BK=32, 4 waves, 4 blocks/CU ----------
// Mechanism: inter-block TLP hides the per-tile vmcnt(0) drain (m114; m97/m103 verified
// 874-912 TF on this structure class at 4096-scale). Adds: granule-rotation swizzle
// (R5/R6: conflicts -> 0), supertile XCD locality, fused RoPE epilogue.
// Schedule per 32-K tile: STAGE(next, other slot) at top; ds_read frags; 16 MFMA;
// vmcnt(0); ONE barrier. (Stage targets slot freed by previous barrier; reads complete
// before barrier via compiler lgkmcnt before MFMA use.)
template <int ROPE>
__global__ __launch_bounds__(256, 4) void k_gemm1(const _Float16* __restrict__ A,
                                                  const _Float16* __restrict__ BT,
                                                  const float* __restrict__ bias,
                                                  _Float16* __restrict__ Cout,
                                                  int M, int N, int K,
                                                  int RGC, int RH, int CW) {
  __shared__ __align__(16) _Float16 sA[2][128 * 32];  // 16 KB
  __shared__ __align__(16) _Float16 sB[2][128 * 32];  // 16 KB
  const int tid = threadIdx.x;
  const int lane = tid & 63;
  const int wid = tid >> 6;      // 0..3
  const int wr = wid >> 1;       // 0..1 (64-row half)
  const int wc = wid & 1;        // 0..1 (64-col half)
  const int lr = lane & 15;
  const int g = lane >> 4;       // k-granule 0..3
  // supertile XCD swizzle (bijective: x=(bm/RH)*RGC+bn/CW, q=(bm%RH)*CW+bn%CW)
  const int bid = blockIdx.x;
  const int x = bid & 7, q = bid >> 3;
  const int bm = (x / RGC) * RH + q / CW;
  const int bn = (x % RGC) * CW + q % CW;
  const size_t arow0 = (size_t)bm * 128;
  const size_t brow0 = (size_t)bn * 128;

  f32x4 acc[4][4];
#pragma unroll
  for (int mi = 0; mi < 4; ++mi)
#pragma unroll
    for (int nj = 0; nj < 4; ++nj) acc[mi][nj] = (f32x4){0.f, 0.f, 0.f, 0.f};

  // stage: 128 rows x 4 granules = 512 granules per operand / 256 thr = 2 rounds each.
  // granule rotation: phys = (g + row/2) & 3 on read; inverse on global source (R5-verified).
  auto STAGE = [&](int slot, int k0) {
#pragma unroll
    for (int r = 0; r < 2; ++r) {
      const int u = tid + r * 256;
      const int row = u >> 2, grl = u & 3;
      const int grn = (grl - (row >> 1)) & 3;
      gload16(A + (arow0 + row) * K + k0 + grn * 8, &sA[slot][u * 8]);
      gload16(BT + (brow0 + row) * K + k0 + grn * 8, &sB[slot][u * 8]);
    }
  };

  STAGE(0, 0);
  asm volatile("s_waitcnt vmcnt(0)" ::: "memory");
  __builtin_amdgcn_s_barrier();

  const int NT = K >> 5;
  for (int t = 0; t < NT; ++t) {
    const int s = t & 1, ns = s ^ 1;
    if (t + 1 < NT) STAGE(ns, (t + 1) << 5);
    f16x8 af[4], bf[4];
#pragma unroll
    for (int mi = 0; mi < 4; ++mi) {
      const int row = wr * 64 + mi * 16 + lr;
      af[mi] = *(const f16x8*)&sA[s][row * 32 + (((g + (row >> 1)) & 3) << 3)];
    }
#pragma unroll
    for (int nj = 0; nj < 4; ++nj) {
      const int row = wc * 64 + nj * 16 + lr;
      bf[nj] = *(const f16x8*)&sB[s][row * 32 + (((g + (row >> 1)) & 3) << 3)];
    }
    __builtin_amdgcn_s_setprio(1);
#pragma unroll
    for (int mi = 0; mi < 4; ++mi)
#pragma unroll
      for (int nj = 0; nj < 4; ++nj)
        acc[mi][nj] = __builtin_amdgcn_mfma_f32_16x16x32_f16(af[mi], bf[nj], acc[mi][nj], 0, 0, 0);
    __builtin_amdgcn_s_setprio(0);
    asm volatile("s_waitcnt vmcnt(0)" ::: "memory");  // next tile landed (drain hidden by TLP)
    __builtin_amdgcn_s_barrier();
  }
  // epilogue: bias + fused RoPE (per-element sincos), direct stores
  const size_t row0 = arow0 + wr * 64;
  const size_t col0 = brow0 + wc * 64;
  const float sgn = (lr & 1) ? 1.f : -1.f;
#pragma unroll
  for (int nj = 0; nj < 4; ++nj) {
    const size_t colbase = col0 + nj * 16;
    const size_t col = colbase + lr;
    const float bv = bias[col];
    const bool dorope = ROPE && (colbase < 2 * C_);  // wave-uniform per nj
    float freq = 0.f;
    if (dorope) {
      const int dp = ((int)(col & 127)) >> 1;
      freq = __expf(-0.14391156831212787f * (float)dp);  // 10000^(-dp/64)
    }
#pragma unroll
    for (int mi = 0; mi < 4; ++mi) {
#pragma unroll
      for (int r = 0; r < 4; ++r) {
        const size_t row = row0 + mi * 16 + g * 4 + r;
        float v = acc[mi][nj][r] + bv;
        if (dorope) {
          const float pe = __shfl_xor(v, 1);  // partner col (col^1), same row
          float sn, cs;
          __sincosf((float)(int)(row & (T_ - 1)) * freq, &sn, &cs);
          v = v * cs + sgn * pe * sn;  // even: xe*cs - xo*sn ; odd: xo*cs + xe*sn
        }
        Cout[row * N + col] = (_Float16)v;
      }
    }
  }
}

// ---------------- fp16 MFMA GEMM, 8-phase + counted vmcnt (GEMM2 path, unchanged) -------------
template <int F16OUT, int NJ, int ROPE>
__global__ __launch_bounds__(512) void k_gemm256(const _Float16* __restrict__ A,
                                                 const _Float16* __restrict__ BT,
                                                 const float* __restrict__ bias,
                                                 void* __restrict__ Cout,
                                                 int M, int N, int K,
                                                 int RGC, int RH, int CW) {
  constexpr int BN = 64 * NJ;
  __shared__ __align__(16) _Float16 sA[2][256 * 64];
  __shared__ __align__(16) _Float16 sB[2][BN * 64];
  const int tid = threadIdx.x;
  const int lane = tid & 63;
  const int wid = tid >> 6;
  const int wr = wid >> 2;
  const int wc = wid & 3;
  const int lr = lane & 15;
  const int g = lane >> 4;
  const int rot = lr & 7;
  const int bid = blockIdx.x;
  const int x = bid & 7, q = bid >> 3;
  const int bm = (x / RGC) * RH + q / CW;
  const int bn = (x % RGC) * CW + q % CW;
  const size_t arow0 = (size_t)bm * 256;
  const size_t brow0 = (size_t)bn * BN;

  f32x4 acc[8][NJ];
#pragma unroll
  for (int mi = 0; mi < 8; ++mi)
#pragma unroll
    for (int nj = 0; nj < NJ; ++nj) acc[mi][nj] = (f32x4){0.f, 0.f, 0.f, 0.f};

  auto STAGE_A = [&](int slot, int k0) {
    const int rord[4] = {0, 2, 1, 3};
#pragma unroll
    for (int ri = 0; ri < 4; ++ri) {
      const int u = tid + rord[ri] * 512;
      const int row = u >> 3, grl = u & 7;
      const int grn = (grl - (row & 7)) & 7;
      gload16(A + (arow0 + row) * K + k0 + grn * 8, &sA[slot][u * 8]);
    }
  };
  auto STAGE_B = [&](int slot, int k0) {
#pragma unroll
    for (int r = 0; r < NJ; ++r) {
      const int u = tid + r * 512;
      const int row = u >> 3, grl = u & 7;
      const int grn = (grl - (row & 7)) & 7;
      gload16(BT + (brow0 + row) * K + k0 + grn * 8, &sB[slot][u * 8]);
    }
  };

  f16x8 af[4], bf[NJ];
  auto LDA = [&](int slot, int mh, int kk) {
#pragma unroll
    for (int mi = 0; mi < 4; ++mi) {
      const int row = wr * 128 + (mh * 4 + mi) * 16 + lr;
      af[mi] = *(const f16x8*)&sA[slot][row * 64 + (((kk * 4 + g + rot) & 7) << 3)];
    }
  };
  auto LDB = [&](int slot, int kk) {
#pragma unroll
    for (int nj = 0; nj < NJ; ++nj) {
      const int row = wc * (16 * NJ) + nj * 16 + lr;
      bf[nj] = *(const f16x8*)&sB[slot][row * 64 + (((kk * 4 + g + rot) & 7) << 3)];
    }
  };
  auto MFMAB = [&](int mh) {
    __builtin_amdgcn_s_setprio(1);
#pragma unroll
    for (int mi = 0; mi < 4; ++mi)
#pragma unroll
      for (int nj = 0; nj < NJ; ++nj)
        acc[mh * 4 + mi][nj] =
            __builtin_amdgcn_mfma_f32_16x16x32_f16(af[mi], bf[nj], acc[mh * 4 + mi][nj], 0, 0, 0);
    __builtin_amdgcn_s_setprio(0);
    __builtin_amdgcn_sched_barrier(0);
  };

  STAGE_B(0, 0);
  STAGE_A(0, 0);
  asm volatile("s_waitcnt vmcnt(2)" ::: "memory");
  __builtin_amdgcn_s_barrier();

  const int NT = K >> 6;
  for (int t = 0; t < NT; ++t) {
    const int s = t & 1, ns = s ^ 1;
    const bool pf = (t + 1 < NT);
    const int kn = (t + 1) << 6;
    LDB(s, 0);
    LDA(s, 0, 0);
    if (pf) STAGE_B(ns, kn);
    __builtin_amdgcn_s_barrier();
    asm volatile("s_waitcnt lgkmcnt(0)" ::: "memory");
    __builtin_amdgcn_sched_barrier(0);
    MFMAB(0);
    if (pf)
      asm volatile("s_waitcnt vmcnt(%0)" ::"i"(NJ) : "memory");
    else
      asm volatile("s_waitcnt vmcnt(0)" ::: "memory");
    __builtin_amdgcn_s_barrier();
    LDA(s, 1, 0);
    if (pf) STAGE_A(ns, kn);
    __builtin_amdgcn_s_barrier();
    asm volatile("s_waitcnt lgkmcnt(0)" ::: "memory");
    __builtin_amdgcn_sched_barrier(0);
    MFMAB(1);
    __builtin_amdgcn_s_barrier();
    LDB(s, 1);
    LDA(s, 0, 1);
    __builtin_amdgcn_s_barrier();
    asm volatile("s_waitcnt lgkmcnt(0)" ::: "memory");
    __builtin_amdgcn_sched_barrier(0);
    MFMAB(0);
    __builtin_amdgcn_s_barrier();
    LDA(s, 1, 1);
    __builtin_amdgcn_s_barrier();
    asm volatile("s_waitcnt lgkmcnt(0)" ::: "memory");
    __builtin_amdgcn_sched_barrier(0);
    MFMAB(1);
    if (pf)
      asm volatile("s_waitcnt vmcnt(2)" ::: "memory");
    __builtin_amdgcn_s_barrier();
  }
  const size_t row0 = arow0 + wr * 128;
  const size_t col0 = brow0 + wc * (16 * NJ);
#pragma unroll
  for (int mi = 0; mi < 8; ++mi) {
#pragma unroll
    for (int nj = 0; nj < NJ; ++nj) {
      const size_t col = col0 + nj * 16 + lr;
      const float bv = bias[col];
#pragma unroll
      for (int r = 0; r < 4; ++r) {
        const size_t row = row0 + mi * 16 + g * 4 + r;
        const float v = acc[mi][nj][r] + bv;
        if (F16OUT)
          ((_Float16*)Cout)[row * N + col] = (_Float16)v;
        else
          ((float*)Cout)[row * N + col] = v;
      }
    }
  }
}

// ---------------- death time d[h][j]: index of 64th beater (T if <64 beaters) ----------------
__global__ __launch_bounds__(256) void k_death(const float* __restrict__ rw, int* __restrict__ dd) {
  const int widG = blockIdx.x * 4 + (threadIdx.x >> 6);
  const int lane = threadIdx.x & 63;
  const int h = widG >> 11, j = widG & (T_ - 1);
  const float* s = rw + h * T_;
  const float sj = s[j];
  int total = 0, d = T_;
  for (int base = 0; base < T_; base += 64) {
    const int t = base + lane;
    const float st = s[t];
    const bool beat = (st > sj) || (st == sj && t < j);
    const unsigned long long bal = __ballot(beat);
    const int c = __popcll(bal);
    if (total + c >= KSP) {
      const int need = KSP - total;
      const int p = __popcll(bal & ((1ull << lane) - 1ull));
      const unsigned long long win = __ballot(beat && (p == need - 1));
      d = base + __builtin_ctzll(win);
      break;
    }
    total += c;
  }
  if (lane == 0) dd[widG] = d;
}

// ---------------- superset key lists per (h, 16-query block) ----------------
__global__ __launch_bounds__(64) void k_slist(const int* __restrict__ dd,
                                              uint32_t* __restrict__ slist) {
  const int bid = blockIdx.x;  // h*128 + qb
  const int qb = bid & 127, h = bid >> 7;
  const int i0 = qb * 16, i1 = i0 + 15;
  const int lane = threadIdx.x;
  const int* dh = dd + h * T_;
  uint32_t* lb = slist + (size_t)bid * 96;
  int total = 0;
  for (int base = 0; base <= i1; base += 64) {
    const int j = base + lane;
    const int dv = dh[j];
    const bool pred = (j <= i1) && (dv > i0);
    const unsigned long long bal = __ballot(pred);
    const int pos = total + __popcll(bal & ((1ull << lane) - 1ull));
    if (pred) lb[pos] = (uint32_t)j | ((uint32_t)dv << 12);
    total += __popcll(bal);
  }
  for (int s = total + lane; s < 96; s += 64) lb[s] = 0;
}

// ---------------- MFMA sparse attention: one wave per (b, h, 16 queries) ----------------
__global__ __launch_bounds__(64, 4) void k_mattn(const _Float16* __restrict__ qkv,
                                                 const uint32_t* __restrict__ slist,
                                                 _Float16* __restrict__ out) {
  __shared__ uint32_t jd[96];
  __shared__ int joff[96];
  __shared__ __align__(16) _Float16 Pl[16 * 104];
  __shared__ __align__(16) _Float16 VT[2048];  // [mt4][lt16][gt4][e8] per (cc,dh) chunk
  const int bid = blockIdx.x;  // b*2048 + h*128 + qb
  const int qb = bid & 127, h = (bid >> 7) & 15, b = bid >> 11;
  const int i0 = qb * 16;
  const int lane = threadIdx.x;
  const int g = lane >> 4, l = lane & 15;
  const uint32_t* lb = slist + (size_t)((h << 7) + qb) * 96;
  {
    const uint32_t pk = lb[lane];
    jd[lane] = pk;
    joff[lane] = (int)(pk & 0xFFFu) * C3;
    if (lane < 32) {
      const uint32_t pk1 = lb[64 + lane];
      jd[64 + lane] = pk1;
      joff[64 + lane] = (int)(pk1 & 0xFFFu) * C3;
    }
  }
  __syncthreads();
  const _Float16* qkvb = qkv + (size_t)b * T_ * C3;
  const _Float16* qrow = qkvb + (size_t)(i0 + l) * C3 + h * D_ + 8 * g;
  f16x8 bq[4];
#pragma unroll
  for (int c = 0; c < 4; ++c) bq[c] = *(const f16x8*)(qrow + 32 * c);
  f32x4 sacc[6];
  const _Float16* kbase = qkvb + C_ + h * D_ + 8 * g;
#pragma unroll
  for (int t = 0; t < 6; ++t) {
    const int jo = joff[16 * t + l];
    const _Float16* kr = kbase + jo;
    f16x8 ak[4];
#pragma unroll
    for (int c = 0; c < 4; ++c) ak[c] = *(const f16x8*)(kr + 32 * c);
    f32x4 a = {0.f, 0.f, 0.f, 0.f};
#pragma unroll
    for (int c = 0; c < 4; ++c)
      a = __builtin_amdgcn_mfma_f32_16x16x32_f16(ak[c], bq[c], a, 0, 0, 0);
    sacc[t] = a;  // S^T[slot 16t+4g+r][query i0+l]
  }
  const int iq = i0 + l;
  float P[6][4];
  float m = -INFINITY;
#pragma unroll
  for (int t = 0; t < 6; ++t)
#pragma unroll
    for (int r = 0; r < 4; ++r) {
      const uint32_t pk = jd[16 * t + 4 * g + r];
      const int j = (int)(pk & 0xFFFu);
      const int d = (int)(pk >> 12);
      const bool ok = (j <= iq) && (d > iq);
      const float x = ok ? sacc[t][r] * 0.08838834764831845f : -INFINITY;
      P[t][r] = x;
      m = fmaxf(m, x);
    }
  m = fmaxf(m, __shfl_xor(m, 16));
  m = fmaxf(m, __shfl_xor(m, 32));
  float ssum = 0.f;
#pragma unroll
  for (int t = 0; t < 6; ++t)
#pragma unroll
    for (int r = 0; r < 4; ++r) {
      const float e = __expf(P[t][r] - m);
      P[t][r] = e;
      ssum += e;
    }
  ssum += __shfl_xor(ssum, 16);
  ssum += __shfl_xor(ssum, 32);
  const float inv = 1.0f / ssum;
#pragma unroll
  for (int t = 0; t < 6; ++t) {
    f16x4 w;
    w.x = (_Float16)(P[t][0] * inv);
    w.y = (_Float16)(P[t][1] * inv);
    w.z = (_Float16)(P[t][2] * inv);
    w.w = (_Float16)(P[t][3] * inv);
    *(f16x4*)&Pl[l * 104 + 16 * t + 4 * g] = w;
  }
  __syncthreads();
  f16x8 pf[3];
#pragma unroll
  for (int cc = 0; cc < 3; ++cc) pf[cc] = *(const f16x8*)&Pl[l * 104 + 32 * cc + 8 * g];
  f32x4 oacc[8];
#pragma unroll
  for (int mt = 0; mt < 8; ++mt) oacc[mt] = (f32x4){0.f, 0.f, 0.f, 0.f};
  const _Float16* vbase = qkvb + 2 * C_ + h * D_;
#pragma unroll
  for (int cc = 0; cc < 3; ++cc) {
    const int jo0 = joff[32 * cc + l];
    const int jo1 = joff[32 * cc + 16 + l];
#pragma unroll
    for (int dh = 0; dh < 2; ++dh) {
      f16x8 vl0[2], vl1[2];
#pragma unroll
      for (int cp = 0; cp < 2; ++cp) {
        vl0[cp] = *(const f16x8*)(vbase + jo0 + 64 * dh + 32 * cp + 8 * g);
        vl1[cp] = *(const f16x8*)(vbase + jo1 + 64 * dh + 32 * cp + 8 * g);
      }
      __syncthreads();
#pragma unroll
      for (int tau = 0; tau < 2; ++tau)
#pragma unroll
        for (int cp = 0; cp < 2; ++cp) {
          const int mtl = 2 * cp + (g >> 1);
          const int lt0 = 8 * (g & 1);
          const int gt = (2 * tau + (l >> 3)) ^ g;
          const int et = l & 7;
#pragma unroll
          for (int e = 0; e < 8; ++e) {
            const int idx = ((mtl * 16 + lt0 + e) * 4 + gt) * 8 + et;
            VT[idx] = tau ? vl1[cp][e] : vl0[cp][e];
          }
        }
      __syncthreads();
#pragma unroll
      for (int mtl = 0; mtl < 4; ++mtl) {
        const int sgr = (l >> 3) | ((mtl & 1) << 1);
        const f16x8 vf = *(const f16x8*)&VT[((mtl * 16 + l) * 4 + (g ^ sgr)) * 8];
        oacc[4 * dh + mtl] =
            __builtin_amdgcn_mfma_f32_16x16x32_f16(pf[cc], vf, oacc[4 * dh + mtl], 0, 0, 0);
      }
    }
  }
  _Float16* ob = out + (size_t)(b * T_ + i0 + 4 * g) * C_ + h * D_ + l;
#pragma unroll
  for (int mt = 0; mt < 8; ++mt)
#pragma unroll
    for (int r = 0; r < 4; ++r)
      ob[(size_t)r * C_ + 16 * mt] = (_Float16)oacc[mt][r];
}

extern "C" void kernel_launch(void* const* d_in, const int* in_sizes, int n_in,
                              void* d_out, int out_size, void* d_ws, size_t ws_size,
                              hipStream_t stream) {
  const float* x  = (const float*)d_in[0];
  const float* Wa = (const float*)d_in[1];
  const float* ba = (const float*)d_in[2];
  const float* Wp = (const float*)d_in[3];
  const float* bp = (const float*)d_in[4];
  const float* rw = (const float*)d_in[5];

  char* ws = (char*)d_ws;
  _Float16* qkv16 = (_Float16*)(ws);                              // 48 MB
  _Float16* WaT   = (_Float16*)(ws + (size_t)48 * 1024 * 1024);   // 24 MB
  _Float16* WpT   = (_Float16*)(ws + (size_t)72 * 1024 * 1024);   //  8 MB
  _Float16* x16   = (_Float16*)(ws + (size_t)80 * 1024 * 1024);   // 16 MB (reused as att16)
  int* dd  = (int*)(ws + (size_t)96 * 1024 * 1024);               // 128 KB
  uint32_t* slist = (uint32_t*)(ws + (size_t)96 * 1024 * 1024 + (2 << 17));  // 786 KB
  _Float16* att16 = x16;  // x16 dead after GEMM1

  // 1. merged prep: x->fp16, Wa->WaT, Wp->WpT (single launch)
  k_prep<<<dim3(18432), dim3(256), 0, stream>>>(x, x16, Wa, WaT, Wp, WpT);
  // 2. qkv = x @ W_attn + b_attn, RoPE fused (fp16): 128x128 tiles, 256 thr,
  //    4 blocks/CU, grid 32x48 = 1536 = 6 exact per-CU; XCD regions 16x12 (RGC=4)
  k_gemm1<1><<<dim3(1536), dim3(256), 0, stream>>>(
      x16, WaT, ba, qkv16, B_ * T_, C3, C_, 4, 16, 12);
  // 3. death times
  k_death<<<dim3(H_ * T_ / 4), dim3(256), 0, stream>>>(rw, dd);
  // 4. superset key lists per (h, 16-query block)
  k_slist<<<dim3(H_ * (T_ / 16)), dim3(64), 0, stream>>>(dd, slist);
  // 5. MFMA sparse attention -> att16
  k_mattn<<<dim3(B_ * H_ * (T_ / 16)), dim3(64), 0, stream>>>(qkv16, slist, att16);
  // 6. out = att @ W_proj + b_proj (f32 out): grid 256; XCD regions 8x4
  k_gemm256<0, 2, 0><<<dim3(256), dim3(512), 0, stream>>>(
      att16, WpT, bp, d_out, B_ * T_, C_, C_, 4, 8, 4);
}

// Round 22
// 239.412 us; speedup vs baseline: 1.0886x; 1.0886x over previous
//
#include <hip/hip_runtime.h>
#include <stdint.h>

#define B_ 2
#define T_ 2048
#define C_ 2048
#define H_ 16
#define D_ 128
#define KSP 64
#define C3 6144   // 3*C_

typedef __attribute__((ext_vector_type(4))) float f32x4;
typedef __attribute__((ext_vector_type(8))) _Float16 f16x8;
typedef __attribute__((ext_vector_type(4))) _Float16 f16x4;
typedef __attribute__((ext_vector_type(2))) _Float16 f16x2;

// global -> LDS async copy, 16B per lane. LDS dest is wave-uniform base + lane*16.
__device__ __forceinline__ void gload16(const void* g, void* l) {
  __builtin_amdgcn_global_load_lds(
      (__attribute__((address_space(1))) void*)(uintptr_t)g,
      (__attribute__((address_space(3))) void*)(uint32_t)(uintptr_t)l,
      16, 0, 0);
}

// ---------------- merged prep: x->f16 cvt + W_attn/W_proj transpose-convert ----------------
// blocks [0,2048): cvt (4096 elem/block = 8.4M total); [2048,14336): Wa tiles; [14336,18432): Wp.
__global__ __launch_bounds__(256) void k_prep(const float* __restrict__ x,
                                              _Float16* __restrict__ x16,
                                              const float* __restrict__ Wa,
                                              _Float16* __restrict__ WaT,
                                              const float* __restrict__ Wp,
                                              _Float16* __restrict__ WpT) {
  __shared__ float tile[32][33];
  const int b = blockIdx.x;
  const int tid = threadIdx.x;
  if (b < 2048) {
    const int base = b * 4096;
#pragma unroll
    for (int p = 0; p < 4; ++p) {
      const int i = base + p * 1024 + tid * 4;
      const float4 v = *(const float4*)(x + i);
      f16x4 o;
      o.x = (_Float16)v.x; o.y = (_Float16)v.y; o.z = (_Float16)v.z; o.w = (_Float16)v.w;
      *(f16x4*)(x16 + i) = o;
    }
    return;
  }
  const float* W;
  _Float16* WT;
  int n0, k0, N;
  if (b < 14336) {
    const int t = b - 2048;          // Wa: 192 x 64 tiles (N=6144, K=2048)
    W = Wa; WT = WaT; N = C3;
    n0 = (t % 192) * 32;
    k0 = (t / 192) * 32;
  } else {
    const int t = b - 14336;         // Wp: 64 x 64 tiles (N=2048, K=2048)
    W = Wp; WT = WpT; N = C_;
    n0 = (t % 64) * 32;
    k0 = (t / 64) * 32;
  }
  const int tx = tid & 31, ty = tid >> 5;  // 32 x 8
#pragma unroll
  for (int r = 0; r < 4; ++r)
    tile[ty + r * 8][tx] = W[(size_t)(k0 + ty + r * 8) * N + n0 + tx];
  __syncthreads();
#pragma unroll
  for (int r = 0; r < 4; ++r)
    WT[(size_t)(n0 + ty + r * 8) * C_ + k0 + tx] = (_Float16)tile[tx][ty + r * 8];
}

// ---------------- fp16 MFMA GEMM, 8-phase + counted vmcnt (session-best config) ----------------
// NJ=3 grid-512 for GEMM1 (fused RoPE, per-element sincos, direct stores);
// NJ=2 grid-256 for GEMM2. Supertile XCD swizzle; counted-vmcnt 4-phase schedule.
template <int F16OUT, int NJ, int ROPE>
__global__ __launch_bounds__(512) void k_gemm256(const _Float16* __restrict__ A,
                                                 const _Float16* __restrict__ BT,
                                                 const float* __restrict__ bias,
                                                 void* __restrict__ Cout,
                                                 int M, int N, int K,
                                                 int RGC, int RH, int CW) {
  constexpr int BN = 64 * NJ;
  __shared__ __align__(16) _Float16 sA[2][256 * 64];
  __shared__ __align__(16) _Float16 sB[2][BN * 64];
  const int tid = threadIdx.x;
  const int lane = tid & 63;
  const int wid = tid >> 6;
  const int wr = wid >> 2;
  const int wc = wid & 3;
  const int lr = lane & 15;
  const int g = lane >> 4;
  const int rot = lr & 7;
  // supertile XCD swizzle
  const int bid = blockIdx.x;
  const int x = bid & 7, q = bid >> 3;
  const int bm = (x / RGC) * RH + q / CW;
  const int bn = (x % RGC) * CW + q % CW;
  const size_t arow0 = (size_t)bm * 256;
  const size_t brow0 = (size_t)bn * BN;

  f32x4 acc[8][NJ];
#pragma unroll
  for (int mi = 0; mi < 8; ++mi)
#pragma unroll
    for (int nj = 0; nj < NJ; ++nj) acc[mi][nj] = (f32x4){0.f, 0.f, 0.f, 0.f};

  auto STAGE_A = [&](int slot, int k0) {
    const int rord[4] = {0, 2, 1, 3};
#pragma unroll
    for (int ri = 0; ri < 4; ++ri) {
      const int u = tid + rord[ri] * 512;
      const int row = u >> 3, grl = u & 7;
      const int grn = (grl - (row & 7)) & 7;
      gload16(A + (arow0 + row) * K + k0 + grn * 8, &sA[slot][u * 8]);
    }
  };
  auto STAGE_B = [&](int slot, int k0) {
#pragma unroll
    for (int r = 0; r < NJ; ++r) {
      const int u = tid + r * 512;
      const int row = u >> 3, grl = u & 7;
      const int grn = (grl - (row & 7)) & 7;
      gload16(BT + (brow0 + row) * K + k0 + grn * 8, &sB[slot][u * 8]);
    }
  };

  f16x8 af[4], bf[NJ];
  auto LDA = [&](int slot, int mh, int kk) {
#pragma unroll
    for (int mi = 0; mi < 4; ++mi) {
      const int row = wr * 128 + (mh * 4 + mi) * 16 + lr;
      af[mi] = *(const f16x8*)&sA[slot][row * 64 + (((kk * 4 + g + rot) & 7) << 3)];
    }
  };
  auto LDB = [&](int slot, int kk) {
#pragma unroll
    for (int nj = 0; nj < NJ; ++nj) {
      const int row = wc * (16 * NJ) + nj * 16 + lr;
      bf[nj] = *(const f16x8*)&sB[slot][row * 64 + (((kk * 4 + g + rot) & 7) << 3)];
    }
  };
  auto MFMAB = [&](int mh) {
    __builtin_amdgcn_s_setprio(1);
#pragma unroll
    for (int mi = 0; mi < 4; ++mi)
#pragma unroll
      for (int nj = 0; nj < NJ; ++nj)
        acc[mh * 4 + mi][nj] =
            __builtin_amdgcn_mfma_f32_16x16x32_f16(af[mi], bf[nj], acc[mh * 4 + mi][nj], 0, 0, 0);
    __builtin_amdgcn_s_setprio(0);
    __builtin_amdgcn_sched_barrier(0);
  };

  STAGE_B(0, 0);
  STAGE_A(0, 0);
  asm volatile("s_waitcnt vmcnt(2)" ::: "memory");
  __builtin_amdgcn_s_barrier();

  const int NT = K >> 6;
  for (int t = 0; t < NT; ++t) {
    const int s = t & 1, ns = s ^ 1;
    const bool pf = (t + 1 < NT);
    const int kn = (t + 1) << 6;
    // ---- phase 0: kk0 mh0 (+B kk0) ; issue STAGE_B(t+1)
    LDB(s, 0);
    LDA(s, 0, 0);
    if (pf) STAGE_B(ns, kn);
    __builtin_amdgcn_s_barrier();
    asm volatile("s_waitcnt lgkmcnt(0)" ::: "memory");
    __builtin_amdgcn_sched_barrier(0);
    MFMAB(0);
    if (pf)
      asm volatile("s_waitcnt vmcnt(%0)" ::"i"(NJ) : "memory");  // a1,a3 of THIS tile landed
    else
      asm volatile("s_waitcnt vmcnt(0)" ::: "memory");
    __builtin_amdgcn_s_barrier();
    // ---- phase 1: kk0 mh1 ; issue STAGE_A(t+1) {a0,a2,a1,a3}
    LDA(s, 1, 0);
    if (pf) STAGE_A(ns, kn);
    __builtin_amdgcn_s_barrier();
    asm volatile("s_waitcnt lgkmcnt(0)" ::: "memory");
    __builtin_amdgcn_sched_barrier(0);
    MFMAB(1);
    __builtin_amdgcn_s_barrier();
    // ---- phase 2: kk1 mh0 (+B kk1)
    LDB(s, 1);
    LDA(s, 0, 1);
    __builtin_amdgcn_s_barrier();
    asm volatile("s_waitcnt lgkmcnt(0)" ::: "memory");
    __builtin_amdgcn_sched_barrier(0);
    MFMAB(0);
    __builtin_amdgcn_s_barrier();
    // ---- phase 3: kk1 mh1 ; counted wait for next tile's (B, a0, a2)
    LDA(s, 1, 1);
    __builtin_amdgcn_s_barrier();
    asm volatile("s_waitcnt lgkmcnt(0)" ::: "memory");
    __builtin_amdgcn_sched_barrier(0);
    MFMAB(1);
    if (pf)
      asm volatile("s_waitcnt vmcnt(2)" ::: "memory");  // a1,a3 of NEXT tile stay in flight
    __builtin_amdgcn_s_barrier();
  }
  // epilogue (+ optional fused RoPE, per-element sincos)
  const size_t row0 = arow0 + wr * 128;
  const size_t col0 = brow0 + wc * (16 * NJ);
  const float sgn = (lr & 1) ? 1.f : -1.f;
#pragma unroll
  for (int nj = 0; nj < NJ; ++nj) {
    const size_t colbase = col0 + nj * 16;
    const size_t col = colbase + lr;
    const float bv = bias[col];
    const bool dorope = ROPE && (colbase < 2 * C_);  // wave-uniform per nj
    float freq = 0.f;
    if (dorope) {
      const int dp = ((int)(col & 127)) >> 1;
      freq = __expf(-0.14391156831212787f * (float)dp);  // 10000^(-dp/64)
    }
#pragma unroll
    for (int mi = 0; mi < 8; ++mi) {
#pragma unroll
      for (int r = 0; r < 4; ++r) {
        const size_t row = row0 + mi * 16 + ((lane >> 4) << 2) + r;
        float v = acc[mi][nj][r] + bv;
        if (dorope) {
          const float pe = __shfl_xor(v, 1);  // partner col (col^1), same row
          float sn, cs;
          __sincosf((float)(int)(row & (T_ - 1)) * freq, &sn, &cs);
          v = v * cs + sgn * pe * sn;  // even: xe*cs - xo*sn ; odd: xo*cs + xe*sn
        }
        if (F16OUT)
          ((_Float16*)Cout)[row * N + col] = (_Float16)v;
        else
          ((float*)Cout)[row * N + col] = v;
      }
    }
  }
}

// ---------------- death time d[h][j]: index of 64th beater (T if <64 beaters) ----------------
__global__ __launch_bounds__(256) void k_death(const float* __restrict__ rw, int* __restrict__ dd) {
  const int widG = blockIdx.x * 4 + (threadIdx.x >> 6);
  const int lane = threadIdx.x & 63;
  const int h = widG >> 11, j = widG & (T_ - 1);
  const float* s = rw + h * T_;
  const float sj = s[j];
  int total = 0, d = T_;
  for (int base = 0; base < T_; base += 64) {
    const int t = base + lane;
    const float st = s[t];
    const bool beat = (st > sj) || (st == sj && t < j);
    const unsigned long long bal = __ballot(beat);
    const int c = __popcll(bal);
    if (total + c >= KSP) {
      const int need = KSP - total;
      const int p = __popcll(bal & ((1ull << lane) - 1ull));
      const unsigned long long win = __ballot(beat && (p == need - 1));
      d = base + __builtin_ctzll(win);
      break;
    }
    total += c;
  }
  if (lane == 0) dd[widG] = d;
}

// ---------------- superset key lists per (h, 16-query block) ----------------
// superset = {j <= i1 : d[h,j] > i0}, |.| <= 79 < 96. pk = j | (d<<12). pad pk=0 (self-masking).
__global__ __launch_bounds__(64) void k_slist(const int* __restrict__ dd,
                                              uint32_t* __restrict__ slist) {
  const int bid = blockIdx.x;  // h*128 + qb
  const int qb = bid & 127, h = bid >> 7;
  const int i0 = qb * 16, i1 = i0 + 15;
  const int lane = threadIdx.x;
  const int* dh = dd + h * T_;
  uint32_t* lb = slist + (size_t)bid * 96;
  int total = 0;
  for (int base = 0; base <= i1; base += 64) {
    const int j = base + lane;
    const int dv = dh[j];
    const bool pred = (j <= i1) && (dv > i0);
    const unsigned long long bal = __ballot(pred);
    const int pos = total + __popcll(bal & ((1ull << lane) - 1ull));
    if (pred) lb[pos] = (uint32_t)j | ((uint32_t)dv << 12);
    total += __popcll(bal);
  }
  for (int s = total + lane; s < 96; s += 64) lb[s] = 0;
}

// ---------------- MFMA sparse attention: one wave per (b, h, 16 queries) ----------------
__global__ __launch_bounds__(64, 4) void k_mattn(const _Float16* __restrict__ qkv,
                                                 const uint32_t* __restrict__ slist,
                                                 _Float16* __restrict__ out) {
  __shared__ uint32_t jd[96];
  __shared__ int joff[96];
  __shared__ __align__(16) _Float16 Pl[16 * 104];
  __shared__ __align__(16) _Float16 VT[2048];  // [mt4][lt16][gt4][e8] per (cc,dh) chunk
  const int bid = blockIdx.x;  // b*2048 + h*128 + qb
  const int qb = bid & 127, h = (bid >> 7) & 15, b = bid >> 11;
  const int i0 = qb * 16;
  const int lane = threadIdx.x;
  const int g = lane >> 4, l = lane & 15;
  const uint32_t* lb = slist + (size_t)((h << 7) + qb) * 96;
  {
    const uint32_t pk = lb[lane];
    jd[lane] = pk;
    joff[lane] = (int)(pk & 0xFFFu) * C3;
    if (lane < 32) {
      const uint32_t pk1 = lb[64 + lane];
      jd[64 + lane] = pk1;
      joff[64 + lane] = (int)(pk1 & 0xFFFu) * C3;
    }
  }
  __syncthreads();
  const _Float16* qkvb = qkv + (size_t)b * T_ * C3;
  const _Float16* qrow = qkvb + (size_t)(i0 + l) * C3 + h * D_ + 8 * g;
  f16x8 bq[4];
#pragma unroll
  for (int c = 0; c < 4; ++c) bq[c] = *(const f16x8*)(qrow + 32 * c);
  f32x4 sacc[6];
  const _Float16* kbase = qkvb + C_ + h * D_ + 8 * g;
#pragma unroll
  for (int t = 0; t < 6; ++t) {
    const int jo = joff[16 * t + l];
    const _Float16* kr = kbase + jo;
    f16x8 ak[4];
#pragma unroll
    for (int c = 0; c < 4; ++c) ak[c] = *(const f16x8*)(kr + 32 * c);
    f32x4 a = {0.f, 0.f, 0.f, 0.f};
#pragma unroll
    for (int c = 0; c < 4; ++c)
      a = __builtin_amdgcn_mfma_f32_16x16x32_f16(ak[c], bq[c], a, 0, 0, 0);
    sacc[t] = a;  // S^T[slot 16t+4g+r][query i0+l]
  }
  const int iq = i0 + l;
  float P[6][4];
  float m = -INFINITY;
#pragma unroll
  for (int t = 0; t < 6; ++t)
#pragma unroll
    for (int r = 0; r < 4; ++r) {
      const uint32_t pk = jd[16 * t + 4 * g + r];
      const int j = (int)(pk & 0xFFFu);
      const int d = (int)(pk >> 12);
      const bool ok = (j <= iq) && (d > iq);
      const float x = ok ? sacc[t][r] * 0.08838834764831845f : -INFINITY;
      P[t][r] = x;
      m = fmaxf(m, x);
    }
  m = fmaxf(m, __shfl_xor(m, 16));
  m = fmaxf(m, __shfl_xor(m, 32));
  float ssum = 0.f;
#pragma unroll
  for (int t = 0; t < 6; ++t)
#pragma unroll
    for (int r = 0; r < 4; ++r) {
      const float e = __expf(P[t][r] - m);
      P[t][r] = e;
      ssum += e;
    }
  ssum += __shfl_xor(ssum, 16);
  ssum += __shfl_xor(ssum, 32);
  const float inv = 1.0f / ssum;
#pragma unroll
  for (int t = 0; t < 6; ++t) {
    f16x4 w;
    w.x = (_Float16)(P[t][0] * inv);
    w.y = (_Float16)(P[t][1] * inv);
    w.z = (_Float16)(P[t][2] * inv);
    w.w = (_Float16)(P[t][3] * inv);
    *(f16x4*)&Pl[l * 104 + 16 * t + 4 * g] = w;
  }
  __syncthreads();
  f16x8 pf[3];
#pragma unroll
  for (int cc = 0; cc < 3; ++cc) pf[cc] = *(const f16x8*)&Pl[l * 104 + 32 * cc + 8 * g];
  f32x4 oacc[8];
#pragma unroll
  for (int mt = 0; mt < 8; ++mt) oacc[mt] = (f32x4){0.f, 0.f, 0.f, 0.f};
  const _Float16* vbase = qkvb + 2 * C_ + h * D_;
#pragma unroll
  for (int cc = 0; cc < 3; ++cc) {
    const int jo0 = joff[32 * cc + l];
    const int jo1 = joff[32 * cc + 16 + l];
#pragma unroll
    for (int dh = 0; dh < 2; ++dh) {
      f16x8 vl0[2], vl1[2];
#pragma unroll
      for (int cp = 0; cp < 2; ++cp) {
        vl0[cp] = *(const f16x8*)(vbase + jo0 + 64 * dh + 32 * cp + 8 * g);
        vl1[cp] = *(const f16x8*)(vbase + jo1 + 64 * dh + 32 * cp + 8 * g);
      }
      __syncthreads();
#pragma unroll
      for (int tau = 0; tau < 2; ++tau)
#pragma unroll
        for (int cp = 0; cp < 2; ++cp) {
          const int mtl = 2 * cp + (g >> 1);
          const int lt0 = 8 * (g & 1);
          const int gt = (2 * tau + (l >> 3)) ^ g;
          const int et = l & 7;
#pragma unroll
          for (int e = 0; e < 8; ++e) {
            const int idx = ((mtl * 16 + lt0 + e) * 4 + gt) * 8 + et;
            VT[idx] = tau ? vl1[cp][e] : vl0[cp][e];
          }
        }
      __syncthreads();
#pragma unroll
      for (int mtl = 0; mtl < 4; ++mtl) {
        const int sgr = (l >> 3) | ((mtl & 1) << 1);
        const f16x8 vf = *(const f16x8*)&VT[((mtl * 16 + l) * 4 + (g ^ sgr)) * 8];
        oacc[4 * dh + mtl] =
            __builtin_amdgcn_mfma_f32_16x16x32_f16(pf[cc], vf, oacc[4 * dh + mtl], 0, 0, 0);
      }
    }
  }
  _Float16* ob = out + (size_t)(b * T_ + i0 + 4 * g) * C_ + h * D_ + l;
#pragma unroll
  for (int mt = 0; mt < 8; ++mt)
#pragma unroll
    for (int r = 0; r < 4; ++r)
      ob[(size_t)r * C_ + 16 * mt] = (_Float16)oacc[mt][r];
}

extern "C" void kernel_launch(void* const* d_in, const int* in_sizes, int n_in,
                              void* d_out, int out_size, void* d_ws, size_t ws_size,
                              hipStream_t stream) {
  const float* x  = (const float*)d_in[0];
  const float* Wa = (const float*)d_in[1];
  const float* ba = (const float*)d_in[2];
  const float* Wp = (const float*)d_in[3];
  const float* bp = (const float*)d_in[4];
  const float* rw = (const float*)d_in[5];

  char* ws = (char*)d_ws;
  _Float16* qkv16 = (_Float16*)(ws);                              // 48 MB
  _Float16* WaT   = (_Float16*)(ws + (size_t)48 * 1024 * 1024);   // 24 MB
  _Float16* WpT   = (_Float16*)(ws + (size_t)72 * 1024 * 1024);   //  8 MB
  _Float16* x16   = (_Float16*)(ws + (size_t)80 * 1024 * 1024);   // 16 MB (reused as att16)
  int* dd  = (int*)(ws + (size_t)96 * 1024 * 1024);               // 128 KB
  uint32_t* slist = (uint32_t*)(ws + (size_t)96 * 1024 * 1024 + (2 << 17));  // 786 KB
  _Float16* att16 = x16;  // x16 dead after GEMM1

  // 1. merged prep: x->fp16, Wa->WaT, Wp->WpT (single launch, 18432 blocks)
  k_prep<<<dim3(18432), dim3(256), 0, stream>>>(x, x16, Wa, WaT, Wp, WpT);
  // 2. qkv = x @ W_attn + b_attn, RoPE fused in epilogue (fp16 out):
  //    256x192 tiles, grid 512; XCD regions 8x8 (RGC=4, RH=8, CW=8)
  k_gemm256<1, 3, 1><<<dim3(512), dim3(512), 0, stream>>>(
      x16, WaT, ba, (void*)qkv16, B_ * T_, C3, C_, 4, 8, 8);
  // 3. death times
  k_death<<<dim3(H_ * T_ / 4), dim3(256), 0, stream>>>(rw, dd);
  // 4. superset key lists per (h, 16-query block)
  k_slist<<<dim3(H_ * (T_ / 16)), dim3(64), 0, stream>>>(dd, slist);
  // 5. MFMA sparse attention -> att16
  k_mattn<<<dim3(B_ * H_ * (T_ / 16)), dim3(64), 0, stream>>>(qkv16, slist, att16);
  // 6. out = att @ W_proj + b_proj (f32 out): grid 256; XCD regions 8x4
  k_gemm256<0, 2, 0><<<dim3(256), dim3(512), 0, stream>>>(
      att16, WpT, bp, d_out, B_ * T_, C_, C_, 4, 8, 4);
}